// Round 6
// baseline (696.199 us; speedup 1.0000x reference)
//
#include <hip/hip_runtime.h>

// ---------------- device-scope grid barrier (persistent blocks) --------------
// Sense: one fetch_add per block (fire-and-forget RMW), last arriver sets a
// release flag, everyone else polls the flag with device-scope atomic LOADS
// (no RMW -> pollers don't serialize the line). Slots zeroed by hipMemsetAsync.
__device__ __forceinline__ void grid_bar(unsigned* bar, int which) {
  __syncthreads();
  if (threadIdx.x == 0) {
    unsigned* cnt = bar + which * 32;   // 128B region per barrier
    unsigned* rel = cnt + 16;
    __threadfence();
    unsigned prev = __hip_atomic_fetch_add(cnt, 1u, __ATOMIC_ACQ_REL,
                                           __HIP_MEMORY_SCOPE_AGENT);
    if (prev == gridDim.x - 1) {
      __hip_atomic_store(rel, 1u, __ATOMIC_RELEASE, __HIP_MEMORY_SCOPE_AGENT);
    } else {
      while (__hip_atomic_load(rel, __ATOMIC_ACQUIRE,
                               __HIP_MEMORY_SCOPE_AGENT) == 0u)
        __builtin_amdgcn_s_sleep(4);
    }
    __threadfence();
  }
  __syncthreads();
}

// ---------- 32x128 tiled GEMM body, 256 threads, 4x4 reg tile ----------
// C[m0+m, col0+n] = sum_k A[(m0+m)*lda + k] * B[k*ldb + col0 + n]
// smem: 16*36 + 16*132 = 2688 floats.
__device__ __forceinline__ void gemm32(
    float* __restrict__ smem,
    const float* __restrict__ A, int lda,
    const float* __restrict__ B, int ldb,
    float* __restrict__ C, int ldc, int K,
    int m0, int col0) {
  float* As = smem;            // [16][36] (k-major, transposed)
  float* Bs = smem + 16 * 36;  // [16][132]
  const int t = threadIdx.x;
  const int tn = t & 31, tm = t >> 5;
  const int lam = t >> 2, lak = (t & 3) * 4;  // threads 0..127 load A
  const int lbk = t >> 4, lbn = (t & 15) * 8;
  float acc[4][4];
#pragma unroll
  for (int i = 0; i < 4; ++i)
#pragma unroll
    for (int j = 0; j < 4; ++j) acc[i][j] = 0.f;
  for (int k0 = 0; k0 < K; k0 += 16) {
    if (t < 128) {
      float4 av = *reinterpret_cast<const float4*>(A + (size_t)(m0 + lam) * lda + k0 + lak);
      As[(lak + 0) * 36 + lam] = av.x;
      As[(lak + 1) * 36 + lam] = av.y;
      As[(lak + 2) * 36 + lam] = av.z;
      As[(lak + 3) * 36 + lam] = av.w;
    }
    const float* bp = B + (size_t)(k0 + lbk) * ldb + col0 + lbn;
    float4 b0 = *reinterpret_cast<const float4*>(bp);
    float4 b1 = *reinterpret_cast<const float4*>(bp + 4);
    float* bd = &Bs[lbk * 132 + lbn];
    *reinterpret_cast<float4*>(bd) = b0;
    *reinterpret_cast<float4*>(bd + 4) = b1;
    __syncthreads();
#pragma unroll
    for (int kk = 0; kk < 16; ++kk) {
      float4 a4 = *reinterpret_cast<const float4*>(&As[kk * 36 + tm * 4]);
      float4 b4 = *reinterpret_cast<const float4*>(&Bs[kk * 132 + tn * 4]);
      float a[4] = {a4.x, a4.y, a4.z, a4.w};
      float b[4] = {b4.x, b4.y, b4.z, b4.w};
#pragma unroll
      for (int i = 0; i < 4; ++i)
#pragma unroll
        for (int j = 0; j < 4; ++j) acc[i][j] = fmaf(a[i], b[j], acc[i][j]);
    }
    __syncthreads();
  }
#pragma unroll
  for (int i = 0; i < 4; ++i) {
    float* cp = C + (size_t)(m0 + tm * 4 + i) * ldc + col0 + tn * 4;
    *reinterpret_cast<float4*>(cp) =
        make_float4(acc[i][0], acc[i][1], acc[i][2], acc[i][3]);
  }
}

// =================== GAT FIN=128 body, split for prefetch pipelining =========
template <int E>
__device__ __forceinline__ void gat128_phase1(
    float* __restrict__ tile, float* __restrict__ partial, const float4* pre,
    const float* __restrict__ waS, const float* __restrict__ waN) {
  constexpr int MR = E + 1;
  constexpr int PASSES = (MR + 7) / 8;
  const int t = threadIdx.x;
  const int el = t >> 5;  // 8 rows per pass (32 threads per row)
  const int f0 = (t & 31) * 4;
  float4 wn[4], ws[4];
#pragma unroll
  for (int h = 0; h < 4; ++h) {
    wn[h] = *reinterpret_cast<const float4*>(waN + h * 128 + f0);
    ws[h] = *reinterpret_cast<const float4*>(waS + h * 128 + f0);
  }
#pragma unroll
  for (int p = 0; p < PASSES; ++p) {
    int e = p * 8 + el;
    if (e < MR) {
      float4 x = pre[p];
      if (e < E) *reinterpret_cast<float4*>(tile + e * 128 + f0) = x;
      float ph[4];
#pragma unroll
      for (int h = 0; h < 4; ++h) {
        float4 w = (e < E) ? wn[h] : ws[h];
        ph[h] = x.x * w.x + x.y * w.y + x.z * w.z + x.w * w.w;
      }
      // 4x4 quad transpose-reduce, then butterfly over the 32-lane row group
      const int b0 = t & 1, b1 = (t >> 1) & 1;
      float m0 = b0 ? ph[1] : ph[0];
      float o0 = b0 ? ph[0] : ph[1];
      float m1 = b0 ? ph[3] : ph[2];
      float o1 = b0 ? ph[2] : ph[3];
      m0 += __shfl_xor(o0, 1);
      m1 += __shfl_xor(o1, 1);
      float mk = b1 ? m1 : m0;
      float gv = b1 ? m0 : m1;
      mk += __shfl_xor(gv, 2);
      mk += __shfl_xor(mk, 4);
      mk += __shfl_xor(mk, 8);
      mk += __shfl_xor(mk, 16);
      if ((t & 31) < 4) partial[e * 4 + (t & 3)] = mk;
    }
  }
}

template <int E>
__device__ __forceinline__ void gat128_phase23(
    const float* __restrict__ tile, const float* __restrict__ partial,
    float* __restrict__ outp) {
  const int t = threadIdx.x;
  const int w = t >> 6, l = t & 63;  // wave = head, lane = neighbor / f-chunk
  float selfl = partial[E * 4 + w];
  float xv = -1e30f;
  if (l < E) {
    float x = selfl + partial[l * 4 + w];
    xv = (x > 0.f) ? x : 0.2f * x;  // LeakyReLU(0.2)
  }
  float m = xv;
  m = fmaxf(m, __shfl_xor(m, 1));
  m = fmaxf(m, __shfl_xor(m, 2));
  m = fmaxf(m, __shfl_xor(m, 4));
  m = fmaxf(m, __shfl_xor(m, 8));
  m = fmaxf(m, __shfl_xor(m, 16));
  m = fmaxf(m, __shfl_xor(m, 32));
  float pz = (l < E) ? __expf(xv - m) : 0.f;
  float s = pz;
  s += __shfl_xor(s, 1);
  s += __shfl_xor(s, 2);
  s += __shfl_xor(s, 4);
  s += __shfl_xor(s, 8);
  s += __shfl_xor(s, 16);
  s += __shfl_xor(s, 32);
  float alpha = pz * (1.f / s);  // lane l holds alpha[e=l]
  float2 acc = make_float2(0.f, 0.f);
#pragma unroll
  for (int e = 0; e < E; ++e) {
    float a = __shfl(alpha, e);
    float2 x = *reinterpret_cast<const float2*>(tile + e * 128 + l * 2);
    acc.x = fmaf(a, x.x, acc.x);
    acc.y = fmaf(a, x.y, acc.y);
  }
  *reinterpret_cast<float2*>(outp + w * 128 + l * 2) = acc;
}

// =================== GAT FIN=512 item (layer 1), same scheme =================
__device__ __forceinline__ void gat512_item(
    float* __restrict__ tile, float* __restrict__ partial,
    const float* __restrict__ xs, const float* __restrict__ xn,
    const float* __restrict__ vaS, const float* __restrict__ vaN,
    float* __restrict__ outp) {
  const int t = threadIdx.x;
  const int el = t >> 7, f0 = (t & 127) * 4;  // 2 rows per pass
  float4 vn[4], vs[4];
#pragma unroll
  for (int h = 0; h < 4; ++h) {
    vn[h] = *reinterpret_cast<const float4*>(vaN + h * 512 + f0);
    vs[h] = *reinterpret_cast<const float4*>(vaS + h * 512 + f0);
  }
#pragma unroll
  for (int p = 0; p < 6; ++p) {
    int e = p * 2 + el;
    if (e < 11) {
      const float* src = (e < 10) ? (xn + (size_t)e * 512 + f0) : (xs + f0);
      float4 x = *reinterpret_cast<const float4*>(src);
      if (e < 10) *reinterpret_cast<float4*>(tile + e * 512 + f0) = x;
      float ph[4];
#pragma unroll
      for (int h = 0; h < 4; ++h) {
        float4 w = (e < 10) ? vn[h] : vs[h];
        ph[h] = x.x * w.x + x.y * w.y + x.z * w.z + x.w * w.w;
      }
      const int b0 = t & 1, b1 = (t >> 1) & 1;
      float m0 = b0 ? ph[1] : ph[0];
      float o0 = b0 ? ph[0] : ph[1];
      float m1 = b0 ? ph[3] : ph[2];
      float o1 = b0 ? ph[2] : ph[3];
      m0 += __shfl_xor(o0, 1);
      m1 += __shfl_xor(o1, 1);
      float mk = b1 ? m1 : m0;
      float gv = b1 ? m0 : m1;
      mk += __shfl_xor(gv, 2);
      mk += __shfl_xor(mk, 4);
      mk += __shfl_xor(mk, 8);
      mk += __shfl_xor(mk, 16);
      mk += __shfl_xor(mk, 32);  // row spans 2 waves -> per-64-half sums
      if ((t & 63) < 4) partial[e * 8 + ((t >> 6) & 1) * 4 + (t & 3)] = mk;
    }
  }
  __syncthreads();
  const int w = t >> 6, l = t & 63;
  float selfl = partial[10 * 8 + w] + partial[10 * 8 + 4 + w];
  float xv = -1e30f;
  if (l < 10) {
    float x = selfl + partial[l * 8 + w] + partial[l * 8 + 4 + w];
    xv = (x > 0.f) ? x : 0.2f * x;
  }
  float m = xv;
  m = fmaxf(m, __shfl_xor(m, 1));
  m = fmaxf(m, __shfl_xor(m, 2));
  m = fmaxf(m, __shfl_xor(m, 4));
  m = fmaxf(m, __shfl_xor(m, 8));
  m = fmaxf(m, __shfl_xor(m, 16));
  m = fmaxf(m, __shfl_xor(m, 32));
  float pz = (l < 10) ? __expf(xv - m) : 0.f;
  float s = pz;
  s += __shfl_xor(s, 1);
  s += __shfl_xor(s, 2);
  s += __shfl_xor(s, 4);
  s += __shfl_xor(s, 8);
  s += __shfl_xor(s, 16);
  s += __shfl_xor(s, 32);
  float alpha = pz * (1.f / s);
  float2 acc[4];
#pragma unroll
  for (int j = 0; j < 4; ++j) acc[j] = make_float2(0.f, 0.f);
#pragma unroll
  for (int e = 0; e < 10; ++e) {
    float a = __shfl(alpha, e);
#pragma unroll
    for (int j = 0; j < 4; ++j) {
      float2 x = *reinterpret_cast<const float2*>(tile + e * 512 + j * 128 + l * 2);
      acc[j].x = fmaf(a, x.x, acc[j].x);
      acc[j].y = fmaf(a, x.y, acc[j].y);
    }
  }
#pragma unroll
  for (int j = 0; j < 4; ++j)
    *reinterpret_cast<float2*>(outp + w * 512 + j * 128 + l * 2) = acc[j];
}

// ======================= single persistent fused kernel =======================
// All stages grid-stride over gridDim.x -> correct for ANY grid size.
__global__ void __launch_bounds__(256, 4) gat_fused(
    const float* __restrict__ h0, const float* __restrict__ h1,
    const float* __restrict__ h2, const float* __restrict__ W0,
    const float* __restrict__ a0s, const float* __restrict__ a0n,
    const float* __restrict__ W1, const float* __restrict__ a1s,
    const float* __restrict__ a1n, const float* __restrict__ Wfc,
    float* __restrict__ wsb, float* __restrict__ out,
    unsigned* __restrict__ bar) {
  __shared__ float smem[5208];  // S2: 10*512 + 88; S1 attn: 3304; gemm: 2688
  const int bid = blockIdx.x;
  const int nG = gridDim.x;
  const int t = threadIdx.x;

  float* wa0s = wsb;              // [4][128]
  float* wa0n = wa0s + 512;       // [4][128]
  float* wa1s = wa0n + 512;       // [4][512]
  float* wa1n = wa1s + 2048;      // [4][512]
  float* va1s = wa1n + 2048;      // [4][4][128]
  float* va1n = va1s + 2048;      // [4][4][128]
  float* T = va1n + 2048;         // [4][512][256] = 524288
  float* Wfinal = T + 524288;     // [4][512][256] = 524288
  float* xagg = Wfinal + 524288;  // [11264][512]  = 5767168
  float* aggx = xagg + 5767168;   // [1024][2048]  = 2097152
  float* Cpart = xagg;            // [16][1024][256] aliased (xagg dead by S3)

  // ---- S0: T gemm (128 items) + wa vectors (20 items) ----
  for (int i = bid; i < 148; i += nG) {
    if (i < 128) {
      int h = i >> 5, mb = (i >> 1) & 15, nb = i & 1;
      gemm32(smem, W1 + h * 128, 512, Wfc + (size_t)h * 32768, 256,
             T + (size_t)h * 131072, 256, 128, mb * 32, nb * 128);
    } else {
      int idx = (i - 128) * 256 + t;  // < 5120
      const float* W; const float* a; float* dst; int ii; int FINW;
      if (idx < 512)       { W = W0; a = a0s; dst = wa0s; ii = idx;        FINW = 128; }
      else if (idx < 1024) { W = W0; a = a0n; dst = wa0n; ii = idx - 512;  FINW = 128; }
      else if (idx < 3072) { W = W1; a = a1s; dst = wa1s; ii = idx - 1024; FINW = 512; }
      else                 { W = W1; a = a1n; dst = wa1n; ii = idx - 3072; FINW = 512; }
      int f = ii >> 2, hh = ii & 3;
      const float* wrow = W + (size_t)f * 512 + hh * 128;
      const float* arow = a + hh * 128;
      float v = 0.f;
#pragma unroll 8
      for (int d = 0; d < 128; ++d) v = fmaf(wrow[d], arow[d], v);
      dst[hh * FINW + f] = v;
    }
    __syncthreads();
  }
  grid_bar(bar, 0);

  // ---- S1 prep: Wfinal gemm (items 0..127) + va (items 128..143) ----
  for (int i = bid; i < 144; i += nG) {
    if (i < 128) {
      int h = i >> 5, h0b = (i >> 3) & 3, mb = (i >> 1) & 3, nb = i & 1;
      gemm32(smem, W0 + h0b * 128, 512,
             T + (size_t)h * 131072 + (size_t)h0b * 32768, 256,
             Wfinal + (size_t)h * 131072 + (size_t)h0b * 32768, 256, 128,
             mb * 32, nb * 128);
    } else {
      int idx = (i - 128) * 256 + t;  // < 4096
      const float* wa = (idx < 2048) ? wa1s : wa1n;
      float* dst = (idx < 2048) ? va1s : va1n;
      int j = idx & 2047;
      int hh = j >> 9, h0b = (j >> 7) & 3, f = j & 127;
      const float* w0row = W0 + (size_t)f * 512 + h0b * 128;
      const float* warow = wa + hh * 512 + h0b * 128;
      float v = 0.f;
#pragma unroll 8
      for (int n = 0; n < 128; ++n) v = fmaf(w0row[n], warow[n], v);
      dst[j] = v;
    }
    __syncthreads();
  }

  // ---- S1 attention: 11264 items, pipelined one-item-lookahead prefetch ----
  {
    const int el = t >> 5, f0 = (t & 31) * 4;
    auto loadPre = [&](int ai, float4* pr) {
      const float* xs; const float* xn; int E;
      if (ai < 10240) { xs = h1 + (size_t)ai * 128; xn = h2 + (size_t)ai * 3200; E = 25; }
      else { int n = ai - 10240; xs = h0 + (size_t)n * 128; xn = h1 + (size_t)n * 1280; E = 10; }
#pragma unroll
      for (int p = 0; p < 4; ++p) {
        int e = p * 8 + el;
        if (e < E) pr[p] = *reinterpret_cast<const float4*>(xn + (size_t)e * 128 + f0);
        else if (e == E) pr[p] = *reinterpret_cast<const float4*>(xs + f0);
      }
    };
    float* tile = smem;
    float* partial = smem + 3200;
    float4 pre[4], pre2[4];
    int a = bid;
    if (a < 11264) loadPre(a, pre);
    while (a < 11264) {
      const bool e25 = (a < 10240);
      if (e25) gat128_phase1<25>(tile, partial, pre, wa0s, wa0n);
      else     gat128_phase1<10>(tile, partial, pre, wa0s, wa0n);
      int nxt = a + nG;
      if (nxt < 11264) loadPre(nxt, pre2);  // in flight across softmax+agg
      __syncthreads();
      float* outp = e25 ? xagg + (size_t)(1024 + a) * 512
                        : xagg + (size_t)(a - 10240) * 512;
      if (e25) gat128_phase23<25>(tile, partial, outp);
      else     gat128_phase23<10>(tile, partial, outp);
      __syncthreads();
#pragma unroll
      for (int p = 0; p < 4; ++p) pre[p] = pre2[p];
      a = nxt;
    }
  }
  grid_bar(bar, 1);

  // ---- S2: layer-1 attention, 1024 items ----
  for (int ii = bid; ii < 1024; ii += nG) {
    gat512_item(smem, smem + 5120, xagg + (size_t)ii * 512,
                xagg + (size_t)(1024 + (size_t)ii * 10) * 512, va1s, va1n,
                aggx + (size_t)ii * 2048);
    __syncthreads();
  }
  grid_bar(bar, 2);

  // ---- S3: out-gemm K-split x16: 16 ks x 32 mb x 2 nb = 1024 items ----
  for (int i = bid; i < 1024; i += nG) {
    int ks = i >> 6, mb = (i >> 1) & 31, nb = i & 1;
    gemm32(smem, aggx + ks * 128, 2048, Wfinal + (size_t)ks * 32768, 256,
           Cpart + (size_t)ks * 262144, 256, 128, mb * 32, nb * 128);
    __syncthreads();
  }
  grid_bar(bar, 3);

  // ---- S4: reduce 16 partials; 65536 float4, grid-stride ----
  for (int i = bid * 256 + t; i < 65536; i += nG * 256) {
    const float4* p = reinterpret_cast<const float4*>(Cpart) + i;
    float4 s = p[0];
#pragma unroll
    for (int ks = 1; ks < 16; ++ks) {
      float4 v = p[(size_t)ks * 65536];
      s.x += v.x; s.y += v.y; s.z += v.z; s.w += v.w;
    }
    reinterpret_cast<float4*>(out)[i] = s;
  }
}

extern "C" void kernel_launch(void* const* d_in, const int* in_sizes, int n_in,
                              void* d_out, int out_size, void* d_ws, size_t ws_size,
                              hipStream_t stream) {
  const float* h0  = (const float*)d_in[0];
  const float* h1  = (const float*)d_in[1];
  const float* h2  = (const float*)d_in[2];
  const float* W0  = (const float*)d_in[3];
  const float* a0s = (const float*)d_in[4];
  const float* a0n = (const float*)d_in[5];
  const float* W1  = (const float*)d_in[6];
  const float* a1s = (const float*)d_in[7];
  const float* a1n = (const float*)d_in[8];
  const float* Wfc = (const float*)d_in[9];
  float* outp = (float*)d_out;

  float* ws = (float*)d_ws;
  // float usage: 9216 small + 2*524288 + 5767168 + 2097152 = 8922112 (35.7 MB)
  // Cpart (16*1024*256 = 4.19M) aliases xagg (5.77M), dead after S2.
  unsigned* bar = (unsigned*)(ws + 8922112);

  // Occupancy-derived grid, computed once (no stream ops; capture-safe).
  static int gridBlocks = 0;
  if (gridBlocks == 0) {
    int occ = 0;
    if (hipOccupancyMaxActiveBlocksPerMultiprocessor(&occ, (const void*)gat_fused,
                                                     256, 0) != hipSuccess ||
        occ < 1)
      occ = 2;
    if (occ > 4) occ = 4;
    gridBlocks = occ * 256;  // 256 CUs on MI355X
  }

  hipMemsetAsync(bar, 0, 512, stream);  // 4 barriers x 128B
  void* args[] = {(void*)&h0,  (void*)&h1,  (void*)&h2,  (void*)&W0,
                  (void*)&a0s, (void*)&a0n, (void*)&W1,  (void*)&a1s,
                  (void*)&a1n, (void*)&Wfc, (void*)&ws,  (void*)&outp,
                  (void*)&bar};
  hipLaunchCooperativeKernel((const void*)gat_fused, dim3(gridBlocks),
                             dim3(256), args, 0, stream);
}

// Round 7
// 256.060 us; speedup vs baseline: 2.7189x; 2.7189x over previous
//
#include <hip/hip_runtime.h>

// ---------- 32x128 tiled GEMM body, 256 threads, 4x4 reg tile ----------
// C[m0+m, col0+n] = sum_k A[(m0+m)*lda + k] * B[k*ldb + col0 + n]
// smem: 16*36 + 16*132 = 2688 floats.
__device__ __forceinline__ void gemm32(
    float* __restrict__ smem,
    const float* __restrict__ A, int lda,
    const float* __restrict__ B, int ldb,
    float* __restrict__ C, int ldc, int K,
    int m0, int col0) {
  float* As = smem;            // [16][36] (k-major, transposed)
  float* Bs = smem + 16 * 36;  // [16][132]
  const int t = threadIdx.x;
  const int tn = t & 31, tm = t >> 5;
  const int lam = t >> 2, lak = (t & 3) * 4;  // threads 0..127 load A
  const int lbk = t >> 4, lbn = (t & 15) * 8;
  float acc[4][4];
#pragma unroll
  for (int i = 0; i < 4; ++i)
#pragma unroll
    for (int j = 0; j < 4; ++j) acc[i][j] = 0.f;
  for (int k0 = 0; k0 < K; k0 += 16) {
    if (t < 128) {
      float4 av = *reinterpret_cast<const float4*>(A + (size_t)(m0 + lam) * lda + k0 + lak);
      As[(lak + 0) * 36 + lam] = av.x;
      As[(lak + 1) * 36 + lam] = av.y;
      As[(lak + 2) * 36 + lam] = av.z;
      As[(lak + 3) * 36 + lam] = av.w;
    }
    const float* bp = B + (size_t)(k0 + lbk) * ldb + col0 + lbn;
    float4 b0 = *reinterpret_cast<const float4*>(bp);
    float4 b1 = *reinterpret_cast<const float4*>(bp + 4);
    float* bd = &Bs[lbk * 132 + lbn];
    *reinterpret_cast<float4*>(bd) = b0;
    *reinterpret_cast<float4*>(bd + 4) = b1;
    __syncthreads();
#pragma unroll
    for (int kk = 0; kk < 16; ++kk) {
      float4 a4 = *reinterpret_cast<const float4*>(&As[kk * 36 + tm * 4]);
      float4 b4 = *reinterpret_cast<const float4*>(&Bs[kk * 132 + tn * 4]);
      float a[4] = {a4.x, a4.y, a4.z, a4.w};
      float b[4] = {b4.x, b4.y, b4.z, b4.w};
#pragma unroll
      for (int i = 0; i < 4; ++i)
#pragma unroll
        for (int j = 0; j < 4; ++j) acc[i][j] = fmaf(a[i], b[j], acc[i][j]);
    }
    __syncthreads();
  }
#pragma unroll
  for (int i = 0; i < 4; ++i) {
    float* cp = C + (size_t)(m0 + tm * 4 + i) * ldc + col0 + tn * 4;
    *reinterpret_cast<float4*>(cp) =
        make_float4(acc[i][0], acc[i][1], acc[i][2], acc[i][3]);
  }
}

// =================== GAT FIN=128 item (one per block), lean body ==============
// Loads issued to registers up-front; 4x4 quad transpose-reduce (7 shfls);
// ONE __syncthreads; per-wave redundant softmax (wave=head, lane=neighbor);
// alpha stays lane-resident, broadcast by __shfl in the aggregate loop.
// smem: E*128 tile + (E+1)*4 partial.
template <int E>
__device__ __forceinline__ void gat128_item(
    float* __restrict__ smem,
    const float* __restrict__ xs, const float* __restrict__ xn,
    const float* __restrict__ waS, const float* __restrict__ waN,
    float* __restrict__ outp) {
  constexpr int MR = E + 1;
  constexpr int PASSES = (MR + 7) / 8;
  float* tile = smem;               // E*128
  float* partial = smem + E * 128;  // MR*4
  const int t = threadIdx.x;
  const int el = t >> 5;            // 8 rows per pass, 32 threads per row
  const int f0 = (t & 31) * 4;
  float4 pre[PASSES];
#pragma unroll
  for (int p = 0; p < PASSES; ++p) {
    int e = p * 8 + el;
    if (e < E) pre[p] = *reinterpret_cast<const float4*>(xn + (size_t)e * 128 + f0);
    else if (e == E) pre[p] = *reinterpret_cast<const float4*>(xs + f0);
  }
  float4 wn[4], ws[4];
#pragma unroll
  for (int h = 0; h < 4; ++h) {
    wn[h] = *reinterpret_cast<const float4*>(waN + h * 128 + f0);
    ws[h] = *reinterpret_cast<const float4*>(waS + h * 128 + f0);
  }
#pragma unroll
  for (int p = 0; p < PASSES; ++p) {
    int e = p * 8 + el;
    if (e < MR) {
      float4 x = pre[p];
      if (e < E) *reinterpret_cast<float4*>(tile + e * 128 + f0) = x;
      float ph[4];
#pragma unroll
      for (int h = 0; h < 4; ++h) {
        float4 w = (e < E) ? wn[h] : ws[h];
        ph[h] = x.x * w.x + x.y * w.y + x.z * w.z + x.w * w.w;
      }
      // 4x4 quad transpose-reduce: lane with (t&3)==h ends with quad sum of h
      const int b0 = t & 1, b1 = (t >> 1) & 1;
      float m0 = b0 ? ph[1] : ph[0];
      float o0 = b0 ? ph[0] : ph[1];
      float m1 = b0 ? ph[3] : ph[2];
      float o1 = b0 ? ph[2] : ph[3];
      m0 += __shfl_xor(o0, 1);
      m1 += __shfl_xor(o1, 1);
      float mk = b1 ? m1 : m0;
      float gv = b1 ? m0 : m1;
      mk += __shfl_xor(gv, 2);
      mk += __shfl_xor(mk, 4);
      mk += __shfl_xor(mk, 8);
      mk += __shfl_xor(mk, 16);
      if ((t & 31) < 4) partial[e * 4 + (t & 3)] = mk;
    }
  }
  __syncthreads();
  const int w = t >> 6, l = t & 63;  // wave = head, lane = neighbor / f-chunk
  float selfl = partial[E * 4 + w];
  float xv = -1e30f;
  if (l < E) {
    float x = selfl + partial[l * 4 + w];
    xv = (x > 0.f) ? x : 0.2f * x;  // LeakyReLU(0.2)
  }
  float m = xv;
  m = fmaxf(m, __shfl_xor(m, 1));
  m = fmaxf(m, __shfl_xor(m, 2));
  m = fmaxf(m, __shfl_xor(m, 4));
  m = fmaxf(m, __shfl_xor(m, 8));
  m = fmaxf(m, __shfl_xor(m, 16));
  m = fmaxf(m, __shfl_xor(m, 32));
  float pz = (l < E) ? __expf(xv - m) : 0.f;
  float s = pz;
  s += __shfl_xor(s, 1);
  s += __shfl_xor(s, 2);
  s += __shfl_xor(s, 4);
  s += __shfl_xor(s, 8);
  s += __shfl_xor(s, 16);
  s += __shfl_xor(s, 32);
  float alpha = pz * (1.f / s);  // lane l holds alpha[e=l]
  float2 acc = make_float2(0.f, 0.f);
#pragma unroll
  for (int e = 0; e < E; ++e) {
    float a = __shfl(alpha, e);
    float2 x = *reinterpret_cast<const float2*>(tile + e * 128 + l * 2);
    acc.x = fmaf(a, x.x, acc.x);
    acc.y = fmaf(a, x.y, acc.y);
  }
  *reinterpret_cast<float2*>(outp + w * 128 + l * 2) = acc;
}

// =================== GAT FIN=512 item (layer 1), same scheme =================
__device__ __forceinline__ void gat512_item(
    float* __restrict__ tile, float* __restrict__ partial,
    const float* __restrict__ xs, const float* __restrict__ xn,
    const float* __restrict__ vaS, const float* __restrict__ vaN,
    float* __restrict__ outp) {
  const int t = threadIdx.x;
  const int el = t >> 7, f0 = (t & 127) * 4;  // 2 rows per pass
  float4 vn[4], vs[4];
#pragma unroll
  for (int h = 0; h < 4; ++h) {
    vn[h] = *reinterpret_cast<const float4*>(vaN + h * 512 + f0);
    vs[h] = *reinterpret_cast<const float4*>(vaS + h * 512 + f0);
  }
#pragma unroll
  for (int p = 0; p < 6; ++p) {
    int e = p * 2 + el;
    if (e < 11) {
      const float* src = (e < 10) ? (xn + (size_t)e * 512 + f0) : (xs + f0);
      float4 x = *reinterpret_cast<const float4*>(src);
      if (e < 10) *reinterpret_cast<float4*>(tile + e * 512 + f0) = x;
      float ph[4];
#pragma unroll
      for (int h = 0; h < 4; ++h) {
        float4 w = (e < 10) ? vn[h] : vs[h];
        ph[h] = x.x * w.x + x.y * w.y + x.z * w.z + x.w * w.w;
      }
      const int b0 = t & 1, b1 = (t >> 1) & 1;
      float m0 = b0 ? ph[1] : ph[0];
      float o0 = b0 ? ph[0] : ph[1];
      float m1 = b0 ? ph[3] : ph[2];
      float o1 = b0 ? ph[2] : ph[3];
      m0 += __shfl_xor(o0, 1);
      m1 += __shfl_xor(o1, 1);
      float mk = b1 ? m1 : m0;
      float gv = b1 ? m0 : m1;
      mk += __shfl_xor(gv, 2);
      mk += __shfl_xor(mk, 4);
      mk += __shfl_xor(mk, 8);
      mk += __shfl_xor(mk, 16);
      mk += __shfl_xor(mk, 32);  // row spans 2 waves -> per-64-half sums
      if ((t & 63) < 4) partial[e * 8 + ((t >> 6) & 1) * 4 + (t & 3)] = mk;
    }
  }
  __syncthreads();
  const int w = t >> 6, l = t & 63;
  float selfl = partial[10 * 8 + w] + partial[10 * 8 + 4 + w];
  float xv = -1e30f;
  if (l < 10) {
    float x = selfl + partial[l * 8 + w] + partial[l * 8 + 4 + w];
    xv = (x > 0.f) ? x : 0.2f * x;
  }
  float m = xv;
  m = fmaxf(m, __shfl_xor(m, 1));
  m = fmaxf(m, __shfl_xor(m, 2));
  m = fmaxf(m, __shfl_xor(m, 4));
  m = fmaxf(m, __shfl_xor(m, 8));
  m = fmaxf(m, __shfl_xor(m, 16));
  m = fmaxf(m, __shfl_xor(m, 32));
  float pz = (l < 10) ? __expf(xv - m) : 0.f;
  float s = pz;
  s += __shfl_xor(s, 1);
  s += __shfl_xor(s, 2);
  s += __shfl_xor(s, 4);
  s += __shfl_xor(s, 8);
  s += __shfl_xor(s, 16);
  s += __shfl_xor(s, 32);
  float alpha = pz * (1.f / s);
  float2 acc[4];
#pragma unroll
  for (int j = 0; j < 4; ++j) acc[j] = make_float2(0.f, 0.f);
#pragma unroll
  for (int e = 0; e < 10; ++e) {
    float a = __shfl(alpha, e);
#pragma unroll
    for (int j = 0; j < 4; ++j) {
      float2 x = *reinterpret_cast<const float2*>(tile + e * 512 + j * 128 + l * 2);
      acc[j].x = fmaf(a, x.x, acc[j].x);
      acc[j].y = fmaf(a, x.y, acc[j].y);
    }
  }
#pragma unroll
  for (int j = 0; j < 4; ++j)
    *reinterpret_cast<float2*>(outp + w * 512 + j * 128 + l * 2) = acc[j];
}

// ======================= prepA: wa vectors + T = W1_hblk @ Wfc_hblk ===========
__global__ void __launch_bounds__(256) prepA(
    const float* __restrict__ W0, const float* __restrict__ a0s,
    const float* __restrict__ a0n,
    const float* __restrict__ W1, const float* __restrict__ a1s,
    const float* __restrict__ a1n, const float* __restrict__ Wfc,
    float* __restrict__ wa0s, float* __restrict__ wa0n,
    float* __restrict__ wa1s, float* __restrict__ wa1n,
    float* __restrict__ T) {
  __shared__ float smem[2688];
  const int b = blockIdx.x;
  if (b < 128) {
    // T[h][k][o] = sum_m W1[k, h*128+m] * Wfc[h*128+m, o]; M=512,K=128,N=256
    int h = b >> 5, mb = (b >> 1) & 15, nb = b & 1;
    gemm32(smem, W1 + h * 128, 512, Wfc + (size_t)h * 32768, 256,
           T + (size_t)h * 131072, 256, 128, mb * 32, nb * 128);
    return;
  }
  int idx = (b - 128) * 256 + threadIdx.x;
  if (idx >= 5120) return;
  const float* W; const float* a; float* dst; int i; int FIN;
  if (idx < 512)       { W = W0; a = a0s; dst = wa0s; i = idx;        FIN = 128; }
  else if (idx < 1024) { W = W0; a = a0n; dst = wa0n; i = idx - 512;  FIN = 128; }
  else if (idx < 3072) { W = W1; a = a1s; dst = wa1s; i = idx - 1024; FIN = 512; }
  else                 { W = W1; a = a1n; dst = wa1n; i = idx - 3072; FIN = 512; }
  int f = i >> 2, h = i & 3;
  const float* wrow = W + (size_t)f * 512 + h * 128;
  const float* arow = a + h * 128;
  float v = 0.f;
#pragma unroll 8
  for (int d = 0; d < 128; ++d) v = fmaf(wrow[d], arow[d], v);
  dst[h * FIN + f] = v;
}

// ==== fusedB: Wfinal gemm (128) + va (16) FIRST, then layer-0 attention ======
__global__ void __launch_bounds__(256) fusedB(
    const float* __restrict__ h0, const float* __restrict__ h1,
    const float* __restrict__ h2, const float* __restrict__ wa0s,
    const float* __restrict__ wa0n, float* __restrict__ xagg,
    const float* __restrict__ W0, const float* __restrict__ wa1s,
    const float* __restrict__ wa1n, const float* __restrict__ T,
    float* __restrict__ va1s, float* __restrict__ va1n,
    float* __restrict__ Wfinal) {
  __shared__ float smem[3304];  // max(attn E=25: 25*128+104, gemm: 2688)
  const int b = blockIdx.x;
  if (b < 128) {
    // Wfinal[h][(h0b*128+f)][o] = sum_n W0[f, h0b*128+n] * T[h][h0b*128+n][o]
    int h = b >> 5, h0b = (b >> 3) & 3, mb = (b >> 1) & 3, nb = b & 1;
    gemm32(smem, W0 + h0b * 128, 512,
           T + (size_t)h * 131072 + (size_t)h0b * 32768, 256,
           Wfinal + (size_t)h * 131072 + (size_t)h0b * 32768, 256, 128,
           mb * 32, nb * 128);
    return;
  }
  if (b < 144) {
    // va1: va[h*512 + h0b*128 + f] = sum_n W0[f, h0b*128+n] * wa1[h*512+h0b*128+n]
    int idx = (b - 128) * 256 + threadIdx.x;  // exactly 4096
    const float* wa = (idx < 2048) ? wa1s : wa1n;
    float* dst = (idx < 2048) ? va1s : va1n;
    int i = idx & 2047;
    int h = i >> 9, h0b = (i >> 7) & 3, f = i & 127;
    const float* w0row = W0 + (size_t)f * 512 + h0b * 128;
    const float* warow = wa + h * 512 + h0b * 128;
    float v = 0.f;
#pragma unroll 8
    for (int n = 0; n < 128; ++n) v = fmaf(w0row[n], warow[n], v);
    dst[i] = v;
    return;
  }
  if (b < 144 + 1024) {
    int n = b - 144;
    gat128_item<10>(smem, h0 + (size_t)n * 128, h1 + (size_t)n * 1280,
                    wa0s, wa0n, xagg + (size_t)n * 512);
    return;
  }
  int g = b - 1168;
  gat128_item<25>(smem, h1 + (size_t)g * 128, h2 + (size_t)g * 3200,
                  wa0s, wa0n, xagg + (size_t)(1024 + g) * 512);
}

// ======================= layer 1 on xagg space ================================
__global__ void __launch_bounds__(256) gat_layer1(
    const float* __restrict__ xagg, const float* __restrict__ vaS,
    const float* __restrict__ vaN, float* __restrict__ aggx) {
  __shared__ float smem[5208];  // 10*512 tile + 11*8 partial
  const int b = blockIdx.x;
  gat512_item(smem, smem + 5120, xagg + (size_t)b * 512,
              xagg + (size_t)(1024 + (size_t)b * 10) * 512, vaS, vaN,
              aggx + (size_t)b * 2048);
}

// ======================= tail: K-split GEMM + reduce ==========================
__global__ void __launch_bounds__(256) gemm_ksplit(
    const float* __restrict__ A, const float* __restrict__ B,
    float* __restrict__ Cpart) {
  __shared__ float smem[2688];
  const int ks = blockIdx.z;
  gemm32(smem, A + ks * 256, 2048, B + (size_t)ks * 65536, 256,
         Cpart + (size_t)ks * 262144, 256, 256, blockIdx.x * 32,
         blockIdx.y * 128);
}

__global__ void __launch_bounds__(256) reduce8(
    const float* __restrict__ Cpart, float* __restrict__ out) {
  int i = blockIdx.x * 256 + threadIdx.x;  // float4 index, 65536 total
  const float4* p = reinterpret_cast<const float4*>(Cpart) + i;
  float4 s = p[0];
#pragma unroll
  for (int ks = 1; ks < 8; ++ks) {
    float4 v = p[(size_t)ks * 65536];
    s.x += v.x; s.y += v.y; s.z += v.z; s.w += v.w;
  }
  reinterpret_cast<float4*>(out)[i] = s;
}

extern "C" void kernel_launch(void* const* d_in, const int* in_sizes, int n_in,
                              void* d_out, int out_size, void* d_ws, size_t ws_size,
                              hipStream_t stream) {
  const float* h0  = (const float*)d_in[0];
  const float* h1  = (const float*)d_in[1];
  const float* h2  = (const float*)d_in[2];
  const float* W0  = (const float*)d_in[3];
  const float* a0s = (const float*)d_in[4];
  const float* a0n = (const float*)d_in[5];
  const float* W1  = (const float*)d_in[6];
  const float* a1s = (const float*)d_in[7];
  const float* a1n = (const float*)d_in[8];
  const float* Wfc = (const float*)d_in[9];
  float* out = (float*)d_out;

  float* ws = (float*)d_ws;
  float* wa0s   = ws;                    // [4][128]
  float* wa0n   = wa0s + 512;            // [4][128]
  float* wa1s   = wa0n + 512;            // [4][512]
  float* wa1n   = wa1s + 2048;           // [4][512]
  float* va1s   = wa1n + 2048;           // [4][4][128]
  float* va1n   = va1s + 2048;           // [4][4][128]
  float* T      = va1n + 2048;           // [4][512][256] = 524288
  float* Wfinal = T + 524288;            // [4][512][256] = 524288
  float* xaggA  = Wfinal + 524288;       // [11264][512]  = 5767168
  float* aggx   = xaggA + 11264 * 512;   // [1024][2048]  = 2097152
  float* Cpart  = aggx + 2097152;        // [8][1024][256]= 2097152
  // total ~11.0M floats = 44.1 MB (same layout as the 263.7us round-1 run)

  // P1: wa vectors + T
  prepA<<<148, 256, 0, stream>>>(W0, a0s, a0n, W1, a1s, a1n, Wfc,
                                 wa0s, wa0n, wa1s, wa1n, T);
  // Wfinal gemm + va first (overlap), then layer-0 attention (both levels)
  fusedB<<<11408, 256, 0, stream>>>(h0, h1, h2, wa0s, wa0n, xaggA,
                                    W0, wa1s, wa1n, T, va1s, va1n, Wfinal);
  // Layer 1 directly in xagg space
  gat_layer1<<<1024, 256, 0, stream>>>(xaggA, va1s, va1n, aggx);
  // Final: out = aggx[1024,2048] @ Wfinal[2048,256], K-split x8 + reduce
  gemm_ksplit<<<dim3(32, 2, 8), 256, 0, stream>>>(aggx, Wfinal, Cpart);
  reduce8<<<256, 256, 0, stream>>>(Cpart, out);
}